// Round 11
// baseline (83.008 us; speedup 1.0000x reference)
//
#include <hip/hip_runtime.h>
#include <cstdint>
#include <cstddef>

#define BATCH  8
#define SEQ    4096
#define CHN    256        // channels (OUT)
#define NQ     768        // 3*OUT
#define KTOT   512        // WIN*IN
#define TS     128        // scan chunk length
#define NCHUNK (SEQ/TS)   // 32
#define SROW   4097       // padded rows per batch in Xbf (row 0 = zeros)

typedef __attribute__((ext_vector_type(8))) __bf16    bf16x8;
typedef __attribute__((ext_vector_type(4))) float     f32x4;
typedef __attribute__((ext_vector_type(4))) _Float16  f16x4;
typedef __attribute__((ext_vector_type(2))) _Float16  f16x2;

#define AS1(p) ((const __attribute__((address_space(1))) void*)(p))
#define AS3(p) ((__attribute__((address_space(3))) void*)(p))

// ---------------------------------------------------------------------------
// K0a: W (fp32 [768][512]) -> frag-major bf16 planes:
//      Wt[tg*768 + n][j] = bf16(W[n][tg*8 + j]),  tg<64, j<8
// ---------------------------------------------------------------------------
__global__ __launch_bounds__(256) void k_convW(const float* __restrict__ W,
                                               __bf16* __restrict__ Wt) {
    int lin = blockIdx.x * 256 + threadIdx.x;   // 0 .. 49151
    int n  = lin % NQ;
    int tg = lin / NQ;
    const float* src = W + (size_t)n * KTOT + tg * 8;
    float4 a = *(const float4*)(src);
    float4 b = *(const float4*)(src + 4);
    bf16x8 h;
    h[0]=(__bf16)a.x; h[1]=(__bf16)a.y; h[2]=(__bf16)a.z; h[3]=(__bf16)a.w;
    h[4]=(__bf16)b.x; h[5]=(__bf16)b.y; h[6]=(__bf16)b.z; h[7]=(__bf16)b.w;
    *(bf16x8*)(Wt + (size_t)lin * 8) = h;
}

// ---------------------------------------------------------------------------
// K0b: x (fp32 [8][4096][256]) -> Xbf ([8][4097][256] bf16, row 0 = zeros)
// ---------------------------------------------------------------------------
__global__ __launch_bounds__(256) void k_convX(const float* __restrict__ x,
                                               __bf16* __restrict__ Xb) {
    int c = blockIdx.x * 256 + threadIdx.x;
    if (c < 8 * 32) {
        int bz = c >> 5, j = c & 31;
        bf16x8 zz = {};
        *(bf16x8*)(Xb + (size_t)bz * SROW * 256 + j * 8) = zz;
    }
    int bi = c >> 17;
    int r  = c & 131071;
    int s  = r >> 5;
    int j  = r & 31;
    const float* src = x + ((size_t)bi * SEQ + s) * 256 + j * 8;
    float4 a = *(const float4*)(src);
    float4 b = *(const float4*)(src + 4);
    bf16x8 h;
    h[0]=(__bf16)a.x; h[1]=(__bf16)a.y; h[2]=(__bf16)a.z; h[3]=(__bf16)a.w;
    h[4]=(__bf16)b.x; h[5]=(__bf16)b.y; h[6]=(__bf16)b.z; h[7]=(__bf16)b.w;
    *(bf16x8*)(Xb + ((size_t)bi * SROW + 1 + s) * 256 + j * 8) = h;
}

__device__ __forceinline__ float fast_sigmoid(float y) {
    float e = __expf(-y);
    return __builtin_amdgcn_rcpf(1.f + e);
}
__device__ __forceinline__ float fast_tanh(float y) {
    float e = __expf(-2.f * y);
    return __builtin_amdgcn_rcpf(1.f + e) * 2.f - 1.f;
}

// ---------------------------------------------------------------------------
// K1: GEMM (y^T = W * xw^T) + activations.  R10 + T4 counted-vmcnt:
//  - per step: issue stage(t+1) -> s_waitcnt vmcnt(N) (N = loads issued THIS
//    step; prior steps' loads thereby landed) -> raw s_barrier -> ds_read+MFMA.
//    NO vmcnt(0) drain in the loop: next-step loads fly across the barrier.
//  - W triple-buffered (write (t+1)%3 never collides with laggard readers of
//    (t-1)%3); X pair double-buffer safe (q+1 vs q-1 differ).
//  - LDS 56KB -> 2 blocks/CU, 3 exact rounds; XCD-pinned grid.
//  Block 256 thr = 4 waves (2s x 2n); tile 128s x 128n; wave 64x64, acc 4x4.
// ---------------------------------------------------------------------------
__global__ __launch_bounds__(256, 2) void k_gemm(
    const __bf16* __restrict__ Xb, const __bf16* __restrict__ Wt,
    const float* __restrict__ bias,
    _Float16* __restrict__ Zb, _Float16* __restrict__ Fb, _Float16* __restrict__ Ob)
{
    __shared__ char XL[2][16384];   // [pairbuf][128 rows][8 c16 x 16B], swizzled
    __shared__ char WL[3][8192];    // [buf3][4 planes][128 n][16B], linear

    int tid = threadIdx.x;
    int bid = blockIdx.x;
    // XCD-pinned decode: bid = i*8 + x ; x = sbt&7 ; i = (sbt>>3)*6 + ngt
    int x_  = bid & 7;
    int i_  = bid >> 3;
    int ngt = i_ % 6;            // n-tile of 128 (gate = ngt>>1)
    int sbt = (i_ / 6) * 8 + x_; // 0..255 s-tile
    int bi  = sbt >> 5;
    int sc  = sbt & 31;
    int s0  = sc * 128;
    int wid = tid >> 6;
    int l   = tid & 63;
    int l15 = l & 15, lg = l >> 4;
    int wr  = wid >> 1;          // s-half (0/1)
    int wc  = wid & 1;           // n-half (0/1)

    // X pair-tile q (covers steps 2q, 2q+1): rows s0..s0+127 (+kh), 64 cols.
    #define STAGE_X(bsel, q)                                                     \
        {                                                                        \
            _Pragma("unroll")                                                    \
            for (int i2 = 0; i2 < 4; ++i2) {                                     \
                int slot = i2 * 256 + tid;                                       \
                int row  = slot >> 3;                                            \
                int c16  = slot & 7;                                             \
                int c16g = c16 ^ (row & 7);                                      \
                const __bf16* gsrc = Xb +                                        \
                    ((size_t)bi * SROW + s0 + row + ((q) >> 2)) * 256            \
                    + ((q) & 3) * 64 + c16g * 8;                                 \
                __builtin_amdgcn_global_load_lds(AS1(gsrc),                      \
                    AS3(XL[bsel] + slot * 16), 16, 0, 0);                        \
            }                                                                    \
        }
    // W tile for step t: planes 4t..4t+3 (each 128n x 16B), linear.
    #define STAGE_W(bsel, t)                                                     \
        {                                                                        \
            _Pragma("unroll")                                                    \
            for (int i2 = 0; i2 < 2; ++i2) {                                     \
                int slot = i2 * 256 + tid;                                       \
                int p  = slot >> 7;                                              \
                int nl = slot & 127;                                             \
                const __bf16* gsrc = Wt +                                        \
                    ((size_t)((t) * 4 + p) * NQ + ngt * 128 + nl) * 8;           \
                __builtin_amdgcn_global_load_lds(AS1(gsrc),                      \
                    AS3(WL[bsel] + slot * 16), 16, 0, 0);                        \
            }                                                                    \
        }

    f32x4 acc[4][4];
    const f32x4 vzero = {0.f, 0.f, 0.f, 0.f};
    #pragma unroll
    for (int a = 0; a < 4; ++a)
        #pragma unroll
        for (int b = 0; b < 4; ++b)
            acc[a][b] = vzero;

    STAGE_X(0, 0);
    STAGE_W(0, 0);
    __syncthreads();                 // prologue: full drain once

    // ---- K loop: 16 t-steps of K=32; counted vmcnt, raw barrier ----
    #pragma unroll
    for (int t = 0; t < 16; ++t) {
        if (t < 15) {
            STAGE_W((t + 1) % 3, t + 1);
            if (t & 1) STAGE_X(((t + 1) >> 1) & 1, (t + 1) >> 1);
        }
        // allow exactly this step's issues to stay in flight
        if (t == 15)      asm volatile("s_waitcnt vmcnt(0)" ::: "memory");
        else if (t & 1)   asm volatile("s_waitcnt vmcnt(6)" ::: "memory");
        else              asm volatile("s_waitcnt vmcnt(2)" ::: "memory");
        __builtin_amdgcn_s_barrier();   // all waves' step-t data landed

        const char* Xc = XL[(t >> 1) & 1];
        const char* Wc = WL[t % 3];
        bf16x8 xf[4], wf[4];
        #pragma unroll
        for (int st = 0; st < 4; ++st) {
            int row = wr * 64 + st * 16 + l15;
            int byte = (row * 128 + ((t & 1) * 4 + lg) * 16) ^ ((row & 7) << 4);
            xf[st] = *(const bf16x8*)(Xc + byte);
        }
        #pragma unroll
        for (int nt = 0; nt < 4; ++nt)
            wf[nt] = *(const bf16x8*)(Wc + lg * 2048
                                         + (wc * 64 + nt * 16 + l15) * 16);
        __builtin_amdgcn_s_setprio(1);
        #pragma unroll
        for (int nt = 0; nt < 4; ++nt)
            #pragma unroll
            for (int st = 0; st < 4; ++st)
                acc[nt][st] = __builtin_amdgcn_mfma_f32_16x16x32_bf16(
                                  wf[nt], xf[st], acc[nt][st], 0, 0, 0);
        __builtin_amdgcn_s_setprio(0);
    }

    __syncthreads();   // full drain; staging LDS free -> epilogue scratch

    // ---- epilogue: activation -> per-wave LDS transpose -> 128B stores ----
    int gate    = ngt >> 1;                    // 0:z 1:f 2:o
    int ch_base = (ngt & 1) * 128 + wc * 64;   // channel base (0..255)
    _Float16* buf = (gate == 0) ? Zb : (gate == 1) ? Fb : Ob;
    char* Sw = (char*)XL + wid * 8192;         // 8KB per-wave scratch (32KB=XL)

    #pragma unroll
    for (int nt = 0; nt < 4; ++nt) {
        float4 bv = *(const float4*)(bias + ngt * 128 + wc * 64 + nt * 16 + lg * 4);
        #pragma unroll
        for (int st = 0; st < 4; ++st) {
            f16x4 hv;
            #pragma unroll
            for (int r = 0; r < 4; ++r) {
                float bvr = (r == 0) ? bv.x : (r == 1) ? bv.y : (r == 2) ? bv.z : bv.w;
                float y = acc[nt][st][r] + bvr;
                float v = (gate == 0) ? fast_tanh(y) : fast_sigmoid(y);
                hv[r] = (_Float16)v;
            }
            int byte = ((st * 16 + l15) * 128 + (nt * 16 + lg * 4) * 2)
                       ^ ((l15 & 7) << 4);
            *(f16x4*)(Sw + byte) = hv;
        }
    }
    #pragma unroll
    for (int so = 0; so < 16; ++so) {
        int s_loc = so * 4 + lg;
        int byte  = (s_loc * 128 + l15 * 8) ^ ((s_loc & 7) << 4);
        f16x4 v = *(const f16x4*)(Sw + byte);
        *(f16x4*)(buf + ((size_t)bi * SEQ + s0 + wr * 64 + s_loc) * CHN
                      + ch_base + l15 * 4) = v;
    }
}

// ---------------------------------------------------------------------------
// K2: per-chunk scan summaries; thread handles 2 channels (4B f16x2 loads).
// ---------------------------------------------------------------------------
__global__ __launch_bounds__(128) void k_scan1(const _Float16* __restrict__ Fb,
                                               const _Float16* __restrict__ Zb,
                                               float* __restrict__ Aq,
                                               float* __restrict__ Bq) {
    int bi = blockIdx.x >> 5;
    int ck = blockIdx.x & 31;
    int c2 = threadIdx.x;
    size_t base = (((size_t)bi * SEQ + ck * TS) * CHN + c2 * 2) >> 1;
    const f16x2* F2 = (const f16x2*)Fb;
    const f16x2* Z2 = (const f16x2*)Zb;
    float a0 = 1.f, a1 = 1.f, c0 = 0.f, c1 = 0.f;
    #pragma unroll 8
    for (int s = 0; s < TS; ++s) {
        f16x2 f = F2[base + (size_t)s * (CHN / 2)];
        f16x2 z = Z2[base + (size_t)s * (CHN / 2)];
        float f0 = (float)f[0], f1 = (float)f[1];
        c0 = f0 * c0 + (1.f - f0) * (float)z[0];
        c1 = f1 * c1 + (1.f - f1) * (float)z[1];
        a0 *= f0; a1 *= f1;
    }
    int o = blockIdx.x * CHN + c2 * 2;
    *(float2*)(Aq + o) = make_float2(a0, a1);
    *(float2*)(Bq + o) = make_float2(c0, c1);
}

// ---------------------------------------------------------------------------
// K3: sequential carry across chunks. 8 blocks x 256 threads, 32 steps.
// ---------------------------------------------------------------------------
__global__ __launch_bounds__(256) void k_scan2(const float* __restrict__ Aq,
                                               const float* __restrict__ Bq,
                                               float* __restrict__ Cq) {
    int bi = blockIdx.x;
    int ch = threadIdx.x;
    float c = 0.f;
    #pragma unroll
    for (int ck = 0; ck < NCHUNK; ++ck) {
        int o = (bi * NCHUNK + ck) * CHN + ch;
        Cq[o] = c;
        c = Aq[o] * c + Bq[o];
    }
}

// ---------------------------------------------------------------------------
// K4: final pass — redo local scan seeded with carry, out = sigmoid(o) * c.
// ---------------------------------------------------------------------------
__global__ __launch_bounds__(128) void k_scan3(const _Float16* __restrict__ Fb,
                                               const _Float16* __restrict__ Zb,
                                               const _Float16* __restrict__ Ob,
                                               const float* __restrict__ Cq,
                                               float* __restrict__ out) {
    int bi = blockIdx.x >> 5;
    int ck = blockIdx.x & 31;
    int c2 = threadIdx.x;
    float2 c = *(const float2*)(Cq + blockIdx.x * CHN + c2 * 2);
    size_t base = (((size_t)bi * SEQ + ck * TS) * CHN + c2 * 2) >> 1;
    const f16x2* F2 = (const f16x2*)Fb;
    const f16x2* Z2 = (const f16x2*)Zb;
    const f16x2* O2 = (const f16x2*)Ob;
    float* outp = out + (((size_t)bi * SEQ + ck * TS) * CHN + c2 * 2);
    #pragma unroll 4
    for (int s = 0; s < TS; ++s) {
        f16x2 f  = F2[base + (size_t)s * (CHN / 2)];
        f16x2 z  = Z2[base + (size_t)s * (CHN / 2)];
        f16x2 so = O2[base + (size_t)s * (CHN / 2)];
        float f0 = (float)f[0], f1 = (float)f[1];
        c.x = f0 * c.x + (1.f - f0) * (float)z[0];
        c.y = f1 * c.y + (1.f - f1) * (float)z[1];
        *(float2*)(outp + (size_t)s * CHN) = make_float2((float)so[0] * c.x,
                                                         (float)so[1] * c.y);
    }
}

// ---------------------------------------------------------------------------
extern "C" void kernel_launch(void* const* d_in, const int* in_sizes, int n_in,
                              void* d_out, int out_size, void* d_ws, size_t ws_size,
                              hipStream_t stream)
{
    const float* x = (const float*)d_in[0];   // (8,4096,256) fp32
    const float* W = (const float*)d_in[1];   // (768,512)    fp32
    const float* b = (const float*)d_in[2];   // (768,)       fp32
    float* out = (float*)d_out;               // (8,4096,256) fp32

    char* ws = (char*)d_ws;
    const size_t MB = 1024 * 1024;
    _Float16* Zb = (_Float16*)(ws +  0 * MB);   // 16 MB
    _Float16* Fb = (_Float16*)(ws + 16 * MB);   // 16 MB
    _Float16* Ob = (_Float16*)(ws + 32 * MB);   // 16 MB
    __bf16*   Wt = (__bf16*)  (ws + 48 * MB);   // 768 KB
    float*    Aq = (float*)   (ws + 49 * MB);   // 256 KB
    float*    Bq = (float*)   (ws + 50 * MB);   // 256 KB
    float*    Cq = (float*)   (ws + 51 * MB);   // 256 KB
    __bf16*   Xb = (__bf16*)  (ws + 52 * MB);   // 16.02 MB

    k_convW<<<dim3(192),            dim3(256), 0, stream>>>(W, Wt);
    k_convX<<<dim3(4096),           dim3(256), 0, stream>>>(x, Xb);
    k_gemm <<<dim3(1536),           dim3(256), 0, stream>>>(Xb, Wt, b, Zb, Fb, Ob);
    k_scan1<<<dim3(BATCH * NCHUNK), dim3(128), 0, stream>>>(Fb, Zb, Aq, Bq);
    k_scan2<<<dim3(BATCH),          dim3(256), 0, stream>>>(Aq, Bq, Cq);
    k_scan3<<<dim3(BATCH * NCHUNK), dim3(128), 0, stream>>>(Fb, Zb, Ob, Cq, out);
}

// Round 12
// 81.711 us; speedup vs baseline: 1.0159x; 1.0159x over previous
//
#include <hip/hip_runtime.h>
#include <cstdint>
#include <cstddef>

#define BATCH  8
#define SEQ    4096
#define CHN    256        // channels (OUT)
#define NQ     768        // 3*OUT
#define KTOT   512        // WIN*IN
#define TS     128        // scan chunk length
#define NCHUNK (SEQ/TS)   // 32
#define SROW   4097       // padded rows per batch in Xbf (row 0 = zeros)

typedef __attribute__((ext_vector_type(8))) __bf16    bf16x8;
typedef __attribute__((ext_vector_type(4))) float     f32x4;
typedef __attribute__((ext_vector_type(4))) _Float16  f16x4;
typedef __attribute__((ext_vector_type(2))) _Float16  f16x2;

#define AS1(p) ((const __attribute__((address_space(1))) void*)(p))
#define AS3(p) ((__attribute__((address_space(3))) void*)(p))

// ---------------------------------------------------------------------------
// K0a: W (fp32 [768][512]) -> frag-major bf16 planes:
//      Wt[tg*768 + n][j] = bf16(W[n][tg*8 + j]),  tg<64, j<8
// ---------------------------------------------------------------------------
__global__ __launch_bounds__(256) void k_convW(const float* __restrict__ W,
                                               __bf16* __restrict__ Wt) {
    int lin = blockIdx.x * 256 + threadIdx.x;   // 0 .. 49151
    int n  = lin % NQ;
    int tg = lin / NQ;
    const float* src = W + (size_t)n * KTOT + tg * 8;
    float4 a = *(const float4*)(src);
    float4 b = *(const float4*)(src + 4);
    bf16x8 h;
    h[0]=(__bf16)a.x; h[1]=(__bf16)a.y; h[2]=(__bf16)a.z; h[3]=(__bf16)a.w;
    h[4]=(__bf16)b.x; h[5]=(__bf16)b.y; h[6]=(__bf16)b.z; h[7]=(__bf16)b.w;
    *(bf16x8*)(Wt + (size_t)lin * 8) = h;
}

// ---------------------------------------------------------------------------
// K0b: x (fp32 [8][4096][256]) -> Xbf ([8][4097][256] bf16, row 0 = zeros)
// ---------------------------------------------------------------------------
__global__ __launch_bounds__(256) void k_convX(const float* __restrict__ x,
                                               __bf16* __restrict__ Xb) {
    int c = blockIdx.x * 256 + threadIdx.x;
    if (c < 8 * 32) {
        int bz = c >> 5, j = c & 31;
        bf16x8 zz = {};
        *(bf16x8*)(Xb + (size_t)bz * SROW * 256 + j * 8) = zz;
    }
    int bi = c >> 17;
    int r  = c & 131071;
    int s  = r >> 5;
    int j  = r & 31;
    const float* src = x + ((size_t)bi * SEQ + s) * 256 + j * 8;
    float4 a = *(const float4*)(src);
    float4 b = *(const float4*)(src + 4);
    bf16x8 h;
    h[0]=(__bf16)a.x; h[1]=(__bf16)a.y; h[2]=(__bf16)a.z; h[3]=(__bf16)a.w;
    h[4]=(__bf16)b.x; h[5]=(__bf16)b.y; h[6]=(__bf16)b.z; h[7]=(__bf16)b.w;
    *(bf16x8*)(Xb + ((size_t)bi * SROW + 1 + s) * 256 + j * 8) = h;
}

__device__ __forceinline__ float fast_sigmoid(float y) {
    float e = __expf(-y);
    return __builtin_amdgcn_rcpf(1.f + e);
}
__device__ __forceinline__ float fast_tanh(float y) {
    float e = __expf(-2.f * y);
    return __builtin_amdgcn_rcpf(1.f + e) * 2.f - 1.f;
}

// ---------------------------------------------------------------------------
// K1: GEMM (y^T = W * xw^T) + activations — mini-m201 8-phase port.
//  Block 512 thr = 8 waves (2 s-halves x 4 n-quarters); tile 128s x 256n
//  (BN = one full gate); wave 64x64, acc 4x4 = 64.
//  K = 8 tiles of BK=64; 3-deep LDS buffers (X 16KB + W 32KB = 48KB each,
//  144KB total, 1 block/CU). Per tile: 4 phases, each
//  {ds_read frags + issue stage(t+2) -> s_barrier -> setprio MFMA x8 -> s_barrier};
//  counted vmcnt(6) ONLY at tile boundaries (never 0 mid-loop).
//  Grid = 3 gates x 256 s-tiles = 768, XCD-pinned, 3 exact CU-rounds.
// ---------------------------------------------------------------------------
__global__ __launch_bounds__(512, 2) void k_gemm(
    const __bf16* __restrict__ Xb, const __bf16* __restrict__ Wt,
    const float* __restrict__ bias,
    _Float16* __restrict__ Zb, _Float16* __restrict__ Fb, _Float16* __restrict__ Ob)
{
    __shared__ char Lds[3][49152];   // per buf: X [0,16K), W [16K,48K)

    int tid = threadIdx.x;
    int bid = blockIdx.x;
    // XCD-pinned decode: bid = i*8 + x ; x = sbt&7 ; i = (sbt>>3)*3 + ngt
    int x_  = bid & 7;
    int i_  = bid >> 3;
    int ngt = i_ % 3;            // gate 0:z 1:f 2:o
    int sbt = (i_ / 3) * 8 + x_; // 0..255 s-tile
    int bi  = sbt >> 5;
    int sc  = sbt & 31;
    int s0  = sc * 128;
    int wid = tid >> 6;
    int l   = tid & 63;
    int l15 = l & 15, lg = l >> 4;
    int wr  = wid >> 2;          // s-half (0/1)
    int wn  = wid & 3;           // n-quarter (0..3)

    // X tile t: [128 rows][8 c16-slots][16B], slot content pre-swizzled so
    // read byte ^ ((row&7)<<4) yields k-group; rows cover win-half t>>2.
    #define STAGE_X8(buf, t)                                                     \
        { _Pragma("unroll")                                                      \
          for (int i2 = 0; i2 < 2; ++i2) {                                       \
              int slot = i2 * 512 + tid;                                         \
              int row  = slot >> 3;                                              \
              int c16  = slot & 7;                                               \
              int c16g = c16 ^ (row & 7);                                        \
              const __bf16* gsrc = Xb +                                          \
                  ((size_t)bi * SROW + s0 + row + ((t) >> 2)) * 256              \
                  + ((t) & 3) * 64 + c16g * 8;                                   \
              __builtin_amdgcn_global_load_lds(AS1(gsrc),                        \
                  AS3(Lds[buf] + slot * 16), 16, 0, 0);                          \
          } }
    // W tile t: 8 planes (8-k groups) x [256 n][16B], linear; quarter i2.
    #define STAGE_W8(buf, t, i2)                                                 \
        { int slot = (i2) * 512 + tid;                                           \
          int p  = slot >> 8;                                                    \
          int nl = slot & 255;                                                   \
          const __bf16* gsrc = Wt +                                              \
              ((size_t)((t) * 8 + p) * NQ + ngt * 256 + nl) * 8;                 \
          __builtin_amdgcn_global_load_lds(AS1(gsrc),                            \
              AS3(Lds[buf] + 16384 + slot * 16), 16, 0, 0); }

    #define LOAD_WF(kk)                                                          \
        { _Pragma("unroll")                                                      \
          for (int nt = 0; nt < 4; ++nt)                                         \
              wf[nt] = *(const bf16x8*)(Wc + ((kk) * 4 + lg) * 4096              \
                                           + (wn * 64 + nt * 16 + l15) * 16); }
    #define LOAD_XF(kk, h2)                                                      \
        { _Pragma("unroll")                                                      \
          for (int q = 0; q < 2; ++q) {                                          \
              int row = wr * 64 + ((h2) * 2 + q) * 16 + l15;                     \
              xf[q] = *(const bf16x8*)(Xc + row * 128                            \
                          + ((((kk) * 4 + lg) ^ (row & 7)) << 4));               \
          } }
    #define MFMA8(h2)                                                            \
        { __builtin_amdgcn_s_setprio(1);                                         \
          _Pragma("unroll")                                                      \
          for (int nt = 0; nt < 4; ++nt) {                                       \
              acc[nt][(h2)*2+0] = __builtin_amdgcn_mfma_f32_16x16x32_bf16(       \
                                      wf[nt], xf[0], acc[nt][(h2)*2+0], 0,0,0);  \
              acc[nt][(h2)*2+1] = __builtin_amdgcn_mfma_f32_16x16x32_bf16(       \
                                      wf[nt], xf[1], acc[nt][(h2)*2+1], 0,0,0);  \
          }                                                                      \
          __builtin_amdgcn_s_setprio(0); }
    #define BAR __builtin_amdgcn_s_barrier()

    f32x4 acc[4][4];
    const f32x4 vzero = {0.f, 0.f, 0.f, 0.f};
    #pragma unroll
    for (int a = 0; a < 4; ++a)
        #pragma unroll
        for (int b = 0; b < 4; ++b)
            acc[a][b] = vzero;

    // ---- prologue: stage tiles 0,1 (12 loads/wave); tile0 landed ----
    STAGE_X8(0, 0);
    STAGE_W8(0, 0, 0); STAGE_W8(0, 0, 1); STAGE_W8(0, 0, 2); STAGE_W8(0, 0, 3);
    STAGE_X8(1, 1);
    STAGE_W8(1, 1, 0); STAGE_W8(1, 1, 1); STAGE_W8(1, 1, 2); STAGE_W8(1, 1, 3);
    asm volatile("s_waitcnt vmcnt(6)" ::: "memory");
    BAR;

    // ---- K loop: 8 tiles x 4 phases; stage(t+2) spread over phases 0-2 ----
    #pragma unroll
    for (int t = 0; t < 8; ++t) {
        const int buf  = t % 3;
        const int nbuf = (t + 2) % 3;
        const char* Xc = Lds[buf];
        const char* Wc = Lds[buf] + 16384;
        bf16x8 wf[4], xf[2];

        // phase 0: kk=0, h2=0
        LOAD_WF(0); LOAD_XF(0, 0);
        if (t < 6) STAGE_X8(nbuf, t + 2);
        BAR; MFMA8(0); BAR;

        // phase 1: kk=0, h2=1
        LOAD_XF(0, 1);
        if (t < 6) { STAGE_W8(nbuf, t + 2, 0); STAGE_W8(nbuf, t + 2, 1); }
        BAR; MFMA8(1); BAR;

        // phase 2: kk=1, h2=0
        LOAD_WF(1); LOAD_XF(1, 0);
        if (t < 6) { STAGE_W8(nbuf, t + 2, 2); STAGE_W8(nbuf, t + 2, 3); }
        BAR; MFMA8(0); BAR;

        // phase 3: kk=1, h2=1 ; tile-boundary counted wait before last barrier
        LOAD_XF(1, 1);
        BAR; MFMA8(1);
        if (t < 6)       asm volatile("s_waitcnt vmcnt(6)" ::: "memory");
        else if (t == 6) asm volatile("s_waitcnt vmcnt(0)" ::: "memory");
        BAR;
    }

    __syncthreads();   // full drain; staging LDS free -> epilogue scratch

    // ---- epilogue: activation -> per-wave LDS transpose -> 128B stores ----
    _Float16* buf = (ngt == 0) ? Zb : (ngt == 1) ? Fb : Ob;
    char* Sw = (char*)Lds + wid * 8192;   // 8KB per-wave scratch (64KB of 144)

    #pragma unroll
    for (int nt = 0; nt < 4; ++nt) {
        float4 bv = *(const float4*)(bias + ngt * 256 + wn * 64 + nt * 16 + lg * 4);
        #pragma unroll
        for (int st = 0; st < 4; ++st) {
            f16x4 hv;
            #pragma unroll
            for (int r = 0; r < 4; ++r) {
                float bvr = (r == 0) ? bv.x : (r == 1) ? bv.y : (r == 2) ? bv.z : bv.w;
                float y = acc[nt][st][r] + bvr;
                float v = (ngt == 0) ? fast_tanh(y) : fast_sigmoid(y);
                hv[r] = (_Float16)v;
            }
            int byte = ((st * 16 + l15) * 128 + (nt * 16 + lg * 4) * 2)
                       ^ ((l15 & 7) << 4);
            *(f16x4*)(Sw + byte) = hv;
        }
    }
    #pragma unroll
    for (int so = 0; so < 16; ++so) {
        int s_loc = so * 4 + lg;
        int byte  = (s_loc * 128 + l15 * 8) ^ ((s_loc & 7) << 4);
        f16x4 v = *(const f16x4*)(Sw + byte);
        *(f16x4*)(buf + ((size_t)bi * SEQ + s0 + wr * 64 + s_loc) * CHN
                      + wn * 64 + l15 * 4) = v;
    }
}

// ---------------------------------------------------------------------------
// K2: per-chunk scan summaries; thread handles 2 channels (4B f16x2 loads).
// ---------------------------------------------------------------------------
__global__ __launch_bounds__(128) void k_scan1(const _Float16* __restrict__ Fb,
                                               const _Float16* __restrict__ Zb,
                                               float* __restrict__ Aq,
                                               float* __restrict__ Bq) {
    int bi = blockIdx.x >> 5;
    int ck = blockIdx.x & 31;
    int c2 = threadIdx.x;
    size_t base = (((size_t)bi * SEQ + ck * TS) * CHN + c2 * 2) >> 1;
    const f16x2* F2 = (const f16x2*)Fb;
    const f16x2* Z2 = (const f16x2*)Zb;
    float a0 = 1.f, a1 = 1.f, c0 = 0.f, c1 = 0.f;
    #pragma unroll 8
    for (int s = 0; s < TS; ++s) {
        f16x2 f = F2[base + (size_t)s * (CHN / 2)];
        f16x2 z = Z2[base + (size_t)s * (CHN / 2)];
        float f0 = (float)f[0], f1 = (float)f[1];
        c0 = f0 * c0 + (1.f - f0) * (float)z[0];
        c1 = f1 * c1 + (1.f - f1) * (float)z[1];
        a0 *= f0; a1 *= f1;
    }
    int o = blockIdx.x * CHN + c2 * 2;
    *(float2*)(Aq + o) = make_float2(a0, a1);
    *(float2*)(Bq + o) = make_float2(c0, c1);
}

// ---------------------------------------------------------------------------
// K3: sequential carry across chunks. 8 blocks x 256 threads, 32 steps.
// ---------------------------------------------------------------------------
__global__ __launch_bounds__(256) void k_scan2(const float* __restrict__ Aq,
                                               const float* __restrict__ Bq,
                                               float* __restrict__ Cq) {
    int bi = blockIdx.x;
    int ch = threadIdx.x;
    float c = 0.f;
    #pragma unroll
    for (int ck = 0; ck < NCHUNK; ++ck) {
        int o = (bi * NCHUNK + ck) * CHN + ch;
        Cq[o] = c;
        c = Aq[o] * c + Bq[o];
    }
}

// ---------------------------------------------------------------------------
// K4: final pass — redo local scan seeded with carry, out = sigmoid(o) * c.
// ---------------------------------------------------------------------------
__global__ __launch_bounds__(128) void k_scan3(const _Float16* __restrict__ Fb,
                                               const _Float16* __restrict__ Zb,
                                               const _Float16* __restrict__ Ob,
                                               const float* __restrict__ Cq,
                                               float* __restrict__ out) {
    int bi = blockIdx.x >> 5;
    int ck = blockIdx.x & 31;
    int c2 = threadIdx.x;
    float2 c = *(const float2*)(Cq + blockIdx.x * CHN + c2 * 2);
    size_t base = (((size_t)bi * SEQ + ck * TS) * CHN + c2 * 2) >> 1;
    const f16x2* F2 = (const f16x2*)Fb;
    const f16x2* Z2 = (const f16x2*)Zb;
    const f16x2* O2 = (const f16x2*)Ob;
    float* outp = out + (((size_t)bi * SEQ + ck * TS) * CHN + c2 * 2);
    #pragma unroll 4
    for (int s = 0; s < TS; ++s) {
        f16x2 f  = F2[base + (size_t)s * (CHN / 2)];
        f16x2 z  = Z2[base + (size_t)s * (CHN / 2)];
        f16x2 so = O2[base + (size_t)s * (CHN / 2)];
        float f0 = (float)f[0], f1 = (float)f[1];
        c.x = f0 * c.x + (1.f - f0) * (float)z[0];
        c.y = f1 * c.y + (1.f - f1) * (float)z[1];
        *(float2*)(outp + (size_t)s * CHN) = make_float2((float)so[0] * c.x,
                                                         (float)so[1] * c.y);
    }
}

// ---------------------------------------------------------------------------
extern "C" void kernel_launch(void* const* d_in, const int* in_sizes, int n_in,
                              void* d_out, int out_size, void* d_ws, size_t ws_size,
                              hipStream_t stream)
{
    const float* x = (const float*)d_in[0];   // (8,4096,256) fp32
    const float* W = (const float*)d_in[1];   // (768,512)    fp32
    const float* b = (const float*)d_in[2];   // (768,)       fp32
    float* out = (float*)d_out;               // (8,4096,256) fp32

    char* ws = (char*)d_ws;
    const size_t MB = 1024 * 1024;
    _Float16* Zb = (_Float16*)(ws +  0 * MB);   // 16 MB
    _Float16* Fb = (_Float16*)(ws + 16 * MB);   // 16 MB
    _Float16* Ob = (_Float16*)(ws + 32 * MB);   // 16 MB
    __bf16*   Wt = (__bf16*)  (ws + 48 * MB);   // 768 KB
    float*    Aq = (float*)   (ws + 49 * MB);   // 256 KB
    float*    Bq = (float*)   (ws + 50 * MB);   // 256 KB
    float*    Cq = (float*)   (ws + 51 * MB);   // 256 KB
    __bf16*   Xb = (__bf16*)  (ws + 52 * MB);   // 16.02 MB

    k_convW<<<dim3(192),            dim3(256), 0, stream>>>(W, Wt);
    k_convX<<<dim3(4096),           dim3(256), 0, stream>>>(x, Xb);
    k_gemm <<<dim3(768),            dim3(512), 0, stream>>>(Xb, Wt, b, Zb, Fb, Ob);
    k_scan1<<<dim3(BATCH * NCHUNK), dim3(128), 0, stream>>>(Fb, Zb, Aq, Bq);
    k_scan2<<<dim3(BATCH),          dim3(256), 0, stream>>>(Aq, Bq, Cq);
    k_scan3<<<dim3(BATCH * NCHUNK), dim3(128), 0, stream>>>(Fb, Zb, Ob, Cq, out);
}

// Round 13
// 81.453 us; speedup vs baseline: 1.0191x; 1.0032x over previous
//
#include <hip/hip_runtime.h>
#include <cstdint>
#include <cstddef>

#define BATCH  8
#define SEQ    4096
#define CHN    256        // channels (OUT)
#define NQ     768        // 3*OUT
#define KTOT   512        // WIN*IN
#define TS     64         // scan chunk length
#define NCHUNK (SEQ/TS)   // 64

typedef __attribute__((ext_vector_type(8))) __bf16    bf16x8;
typedef __attribute__((ext_vector_type(4))) float     f32x4;
typedef __attribute__((ext_vector_type(4))) _Float16  f16x4;
typedef __attribute__((ext_vector_type(2))) _Float16  f16x2;

#define AS1(p) ((const __attribute__((address_space(1))) void*)(p))
#define AS3(p) ((__attribute__((address_space(3))) void*)(p))

// ---------------------------------------------------------------------------
// K0: W (fp32 [768][512]) -> frag-major bf16 planes:
//     Wt[tg*768 + n][j] = bf16(W[n][tg*8 + j]),  tg<64, j<8
// ---------------------------------------------------------------------------
__global__ __launch_bounds__(256) void k_convW(const float* __restrict__ W,
                                               __bf16* __restrict__ Wt) {
    int lin = blockIdx.x * 256 + threadIdx.x;   // 0 .. 49151
    int n  = lin % NQ;
    int tg = lin / NQ;
    const float* src = W + (size_t)n * KTOT + tg * 8;
    float4 a = *(const float4*)(src);
    float4 b = *(const float4*)(src + 4);
    bf16x8 h;
    h[0]=(__bf16)a.x; h[1]=(__bf16)a.y; h[2]=(__bf16)a.z; h[3]=(__bf16)a.w;
    h[4]=(__bf16)b.x; h[5]=(__bf16)b.y; h[6]=(__bf16)b.z; h[7]=(__bf16)b.w;
    *(bf16x8*)(Wt + (size_t)lin * 8) = h;
}

__device__ __forceinline__ float fast_sigmoid(float y) {
    float e = __expf(-y);
    return __builtin_amdgcn_rcpf(1.f + e);
}
__device__ __forceinline__ float fast_tanh(float y) {
    float e = __expf(-2.f * y);
    return __builtin_amdgcn_rcpf(1.f + e) * 2.f - 1.f;
}

// ---------------------------------------------------------------------------
// K1: GEMM (y^T = W * xw^T) + activations — max-TLP variant of R10:
//  - block 256 thr = 4 waves (2 s x 2 n); block tile 64s x 128n;
//    wave tile 32s x 64n -> acc 4nt x 2st = 32 regs.
//  - LDS: X 2x8KB (pair-tiles, swizzled) + W 2x8KB = 32KB ->
//    launch_bounds(256,4): 4 blocks/CU co-resident, 16 waves/CU (Occ ~50%).
//  - X staged from fp32 x IN-KERNEL (reg-stage: load->cvt->swizzled ds_write;
//    same LDS image as R10; convX kernel eliminated). W via global_load_lds.
//  - 16 K-steps of 32; stage(t+1) before compute(t); one __syncthreads per
//    step (proven R10 overlap); no setprio (m190).
//  - XCD-pinned grid: 6 gates x 512 s-tiles = 3072 blocks.
// ---------------------------------------------------------------------------
__global__ __launch_bounds__(256, 4) void k_gemm(
    const float* __restrict__ x, const __bf16* __restrict__ Wt,
    const float* __restrict__ bias,
    _Float16* __restrict__ Zb, _Float16* __restrict__ Fb, _Float16* __restrict__ Ob)
{
    __shared__ char XL[2][8192];    // [pairbuf][64 rows][8 c16 x 16B], swizzled
    __shared__ char WL[2][8192];    // [buf][4 planes][128 n][16B], linear

    int tid = threadIdx.x;
    int bid = blockIdx.x;
    // XCD-pinned decode: bid = i*8 + x_ ; x_ = sbt&7 ; i = (sbt>>3)*6 + ngt
    int x_  = bid & 7;
    int i_  = bid >> 3;
    int ngt = i_ % 6;            // n-tile of 128 (gate = ngt>>1)
    int sbt = (i_ / 6) * 8 + x_; // 0..511 s-tile
    int bi  = sbt >> 6;
    int sc  = sbt & 63;
    int s0  = sc * 64;
    int wid = tid >> 6;
    int l   = tid & 63;
    int l15 = l & 15, lg = l >> 4;
    int wr  = wid >> 1;          // s-half (0/1): rows [32*wr, +32)
    int wc  = wid & 1;           // n-half (0/1): cols [64*wc, +64)

    // ---- X pair-tile q (covers steps 2q,2q+1): 512 slots of 16B.
    // slot=(row 0..63, c16 0..7); LDS slot holds global col16 c16^(row&7)
    // (same image as R10's pre-swizzled gload_lds). Source is fp32 x,
    // converted in-register; row_x = s0+row+(q>>2)-1, zero if < 0.
    float4 xa[2], xb[2];
    #define XLOAD(q)                                                             \
        { _Pragma("unroll")                                                      \
          for (int i2 = 0; i2 < 2; ++i2) {                                       \
              int slot = i2 * 256 + tid;                                         \
              int row  = slot >> 3;                                              \
              int c16g = (slot & 7) ^ (row & 7);                                 \
              int row_x = s0 + row + ((q) >> 2) - 1;                             \
              if (row_x >= 0) {                                                  \
                  const float* src = x + ((size_t)bi * SEQ + row_x) * 256        \
                                       + ((q) & 3) * 64 + c16g * 8;              \
                  xa[i2] = *(const float4*)src;                                  \
                  xb[i2] = *(const float4*)(src + 4);                            \
              } else {                                                           \
                  xa[i2] = make_float4(0.f, 0.f, 0.f, 0.f);                      \
                  xb[i2] = xa[i2];                                               \
              }                                                                  \
          } }
    #define XWRITE(bsel)                                                         \
        { _Pragma("unroll")                                                      \
          for (int i2 = 0; i2 < 2; ++i2) {                                       \
              int slot = i2 * 256 + tid;                                         \
              bf16x8 h;                                                          \
              h[0]=(__bf16)xa[i2].x; h[1]=(__bf16)xa[i2].y;                      \
              h[2]=(__bf16)xa[i2].z; h[3]=(__bf16)xa[i2].w;                      \
              h[4]=(__bf16)xb[i2].x; h[5]=(__bf16)xb[i2].y;                      \
              h[6]=(__bf16)xb[i2].z; h[7]=(__bf16)xb[i2].w;                      \
              *(bf16x8*)(XL[bsel] + slot * 16) = h;                              \
          } }
    // W tile for step t: planes 4t..4t+3 (each 128n x 16B), linear.
    #define STAGE_W(bsel, t)                                                     \
        { _Pragma("unroll")                                                      \
          for (int i2 = 0; i2 < 2; ++i2) {                                       \
              int slot = i2 * 256 + tid;                                         \
              int p  = slot >> 7;                                                \
              int nl = slot & 127;                                               \
              const __bf16* gsrc = Wt +                                          \
                  ((size_t)((t) * 4 + p) * NQ + ngt * 128 + nl) * 8;             \
              __builtin_amdgcn_global_load_lds(AS1(gsrc),                        \
                  AS3(WL[bsel] + slot * 16), 16, 0, 0);                          \
          } }

    f32x4 acc[4][2];
    const f32x4 vzero = {0.f, 0.f, 0.f, 0.f};
    #pragma unroll
    for (int a = 0; a < 4; ++a)
        #pragma unroll
        for (int b = 0; b < 2; ++b)
            acc[a][b] = vzero;

    XLOAD(0); XWRITE(0);
    STAGE_W(0, 0);
    __syncthreads();                 // X pair 0 + W step 0 ready

    // ---- K loop: 16 t-steps of K=32; stage-ahead, 1 barrier per step ----
    #pragma unroll
    for (int t = 0; t < 16; ++t) {
        if (t < 15) {
            STAGE_W((t + 1) & 1, t + 1);
            if (t & 1) XLOAD((t + 1) >> 1);       // issue early (overlaps MFMA)
        }

        const char* Xc = XL[(t >> 1) & 1];
        const char* Wc = WL[t & 1];
        bf16x8 xf[2], wf[4];
        #pragma unroll
        for (int st = 0; st < 2; ++st) {
            int row = wr * 32 + st * 16 + l15;
            int byte = (row * 128 + ((t & 1) * 4 + lg) * 16) ^ ((row & 7) << 4);
            xf[st] = *(const bf16x8*)(Xc + byte);
        }
        #pragma unroll
        for (int nt = 0; nt < 4; ++nt)
            wf[nt] = *(const bf16x8*)(Wc + lg * 2048
                                         + (wc * 64 + nt * 16 + l15) * 16);
        #pragma unroll
        for (int nt = 0; nt < 4; ++nt)
            #pragma unroll
            for (int st = 0; st < 2; ++st)
                acc[nt][st] = __builtin_amdgcn_mfma_f32_16x16x32_bf16(
                                  wf[nt], xf[st], acc[nt][st], 0, 0, 0);

        if ((t & 1) && t < 15) XWRITE(((t + 1) >> 1) & 1);   // other pair-buf

        __syncthreads();             // step-t reads retired; t+1 stages landed
    }

    __syncthreads();   // staging LDS free -> epilogue scratch

    // ---- epilogue: activation -> per-wave LDS transpose -> 128B stores ----
    int gate    = ngt >> 1;                    // 0:z 1:f 2:o
    int ch_base = (ngt & 1) * 128 + wc * 64;   // channel base (0..255)
    _Float16* buf = (gate == 0) ? Zb : (gate == 1) ? Fb : Ob;
    char* Sw = (char*)XL + wid * 4096;         // 4KB per-wave scratch

    #pragma unroll
    for (int nt = 0; nt < 4; ++nt) {
        float4 bv = *(const float4*)(bias + ngt * 128 + wc * 64 + nt * 16 + lg * 4);
        #pragma unroll
        for (int st = 0; st < 2; ++st) {
            f16x4 hv;
            #pragma unroll
            for (int r = 0; r < 4; ++r) {
                float bvr = (r == 0) ? bv.x : (r == 1) ? bv.y : (r == 2) ? bv.z : bv.w;
                float y = acc[nt][st][r] + bvr;
                float v = (gate == 0) ? fast_tanh(y) : fast_sigmoid(y);
                hv[r] = (_Float16)v;
            }
            int byte = ((st * 16 + l15) * 128 + (nt * 16 + lg * 4) * 2)
                       ^ ((l15 & 7) << 4);
            *(f16x4*)(Sw + byte) = hv;
        }
    }
    #pragma unroll
    for (int so = 0; so < 8; ++so) {
        int s_loc = so * 4 + lg;               // 0..31
        int byte  = (s_loc * 128 + l15 * 8) ^ ((s_loc & 7) << 4);
        f16x4 v = *(const f16x4*)(Sw + byte);
        *(f16x4*)(buf + ((size_t)bi * SEQ + s0 + wr * 32 + s_loc) * CHN
                      + ch_base + l15 * 4) = v;
    }
}

// ---------------------------------------------------------------------------
// K2: per-chunk scan summaries; thread handles 2 channels (4B f16x2 loads).
// ---------------------------------------------------------------------------
__global__ __launch_bounds__(128) void k_scan1(const _Float16* __restrict__ Fb,
                                               const _Float16* __restrict__ Zb,
                                               float* __restrict__ Aq,
                                               float* __restrict__ Bq) {
    int bi = blockIdx.x >> 6;
    int ck = blockIdx.x & 63;
    int c2 = threadIdx.x;
    size_t base = (((size_t)bi * SEQ + ck * TS) * CHN + c2 * 2) >> 1;
    const f16x2* F2 = (const f16x2*)Fb;
    const f16x2* Z2 = (const f16x2*)Zb;
    float a0 = 1.f, a1 = 1.f, c0 = 0.f, c1 = 0.f;
    #pragma unroll 8
    for (int s = 0; s < TS; ++s) {
        f16x2 f = F2[base + (size_t)s * (CHN / 2)];
        f16x2 z = Z2[base + (size_t)s * (CHN / 2)];
        float f0 = (float)f[0], f1 = (float)f[1];
        c0 = f0 * c0 + (1.f - f0) * (float)z[0];
        c1 = f1 * c1 + (1.f - f1) * (float)z[1];
        a0 *= f0; a1 *= f1;
    }
    int o = blockIdx.x * CHN + c2 * 2;
    *(float2*)(Aq + o) = make_float2(a0, a1);
    *(float2*)(Bq + o) = make_float2(c0, c1);
}

// ---------------------------------------------------------------------------
// K3: sequential carry across chunks. 8 blocks x 256 threads, 64 steps.
// ---------------------------------------------------------------------------
__global__ __launch_bounds__(256) void k_scan2(const float* __restrict__ Aq,
                                               const float* __restrict__ Bq,
                                               float* __restrict__ Cq) {
    int bi = blockIdx.x;
    int ch = threadIdx.x;
    float c = 0.f;
    #pragma unroll
    for (int ck = 0; ck < NCHUNK; ++ck) {
        int o = (bi * NCHUNK + ck) * CHN + ch;
        Cq[o] = c;
        c = Aq[o] * c + Bq[o];
    }
}

// ---------------------------------------------------------------------------
// K4: final pass — redo local scan seeded with carry, out = sigmoid(o) * c.
// ---------------------------------------------------------------------------
__global__ __launch_bounds__(128) void k_scan3(const _Float16* __restrict__ Fb,
                                               const _Float16* __restrict__ Zb,
                                               const _Float16* __restrict__ Ob,
                                               const float* __restrict__ Cq,
                                               float* __restrict__ out) {
    int bi = blockIdx.x >> 6;
    int ck = blockIdx.x & 63;
    int c2 = threadIdx.x;
    float2 c = *(const float2*)(Cq + blockIdx.x * CHN + c2 * 2);
    size_t base = (((size_t)bi * SEQ + ck * TS) * CHN + c2 * 2) >> 1;
    const f16x2* F2 = (const f16x2*)Fb;
    const f16x2* Z2 = (const f16x2*)Zb;
    const f16x2* O2 = (const f16x2*)Ob;
    float* outp = out + (((size_t)bi * SEQ + ck * TS) * CHN + c2 * 2);
    #pragma unroll 4
    for (int s = 0; s < TS; ++s) {
        f16x2 f  = F2[base + (size_t)s * (CHN / 2)];
        f16x2 z  = Z2[base + (size_t)s * (CHN / 2)];
        f16x2 so = O2[base + (size_t)s * (CHN / 2)];
        float f0 = (float)f[0], f1 = (float)f[1];
        c.x = f0 * c.x + (1.f - f0) * (float)z[0];
        c.y = f1 * c.y + (1.f - f1) * (float)z[1];
        *(float2*)(outp + (size_t)s * CHN) = make_float2((float)so[0] * c.x,
                                                         (float)so[1] * c.y);
    }
}

// ---------------------------------------------------------------------------
extern "C" void kernel_launch(void* const* d_in, const int* in_sizes, int n_in,
                              void* d_out, int out_size, void* d_ws, size_t ws_size,
                              hipStream_t stream)
{
    const float* x = (const float*)d_in[0];   // (8,4096,256) fp32
    const float* W = (const float*)d_in[1];   // (768,512)    fp32
    const float* b = (const float*)d_in[2];   // (768,)       fp32
    float* out = (float*)d_out;               // (8,4096,256) fp32

    char* ws = (char*)d_ws;
    const size_t MB = 1024 * 1024;
    _Float16* Zb = (_Float16*)(ws +  0 * MB);   // 16 MB
    _Float16* Fb = (_Float16*)(ws + 16 * MB);   // 16 MB
    _Float16* Ob = (_Float16*)(ws + 32 * MB);   // 16 MB
    __bf16*   Wt = (__bf16*)  (ws + 48 * MB);   // 768 KB
    float*    Aq = (float*)   (ws + 49 * MB);   // 512 KB
    float*    Bq = (float*)   (ws + 50 * MB);   // 512 KB
    float*    Cq = (float*)   (ws + 51 * MB);   // 512 KB

    k_convW<<<dim3(192),            dim3(256), 0, stream>>>(W, Wt);
    k_gemm <<<dim3(3072),           dim3(256), 0, stream>>>(x, Wt, b, Zb, Fb, Ob);
    k_scan1<<<dim3(BATCH * NCHUNK), dim3(128), 0, stream>>>(Fb, Zb, Aq, Bq);
    k_scan2<<<dim3(BATCH),          dim3(256), 0, stream>>>(Aq, Bq, Cq);
    k_scan3<<<dim3(BATCH * NCHUNK), dim3(128), 0, stream>>>(Fb, Zb, Ob, Cq, out);
}